// Round 4
// baseline (288.301 us; speedup 1.0000x reference)
//
#include <hip/hip_runtime.h>

#define B_DIM 32768
#define IN_DIM 1024
#define OUT_DIM 1024

typedef int v4i __attribute__((ext_vector_type(4)));
typedef int v16i __attribute__((ext_vector_type(16)));

__device__ __forceinline__ int sgnb(float v) {
    return (v > 0.f) ? 1 : ((v < 0.f) ? 0xff : 0);
}
__device__ __forceinline__ int gsgnb(float w, float g) {
    return (g < 0.f) ? 0 : sgnb(w);
}

// Blocks [0, 8192): binarize x rows (4 rows/block, 1 wave/row) + in_scale.
// Blocks [8192, 8448): binarize weight*gate rows + weight_scale.
__global__ __launch_bounds__(256) void prep_kernel(
    const float* __restrict__ x, const float* __restrict__ w,
    const float* __restrict__ g,
    signed char* __restrict__ sx, signed char* __restrict__ wb,
    float* __restrict__ xscale, float* __restrict__ wscale) {
    const int wave = threadIdx.x >> 6;
    const int lane = threadIdx.x & 63;
    const int bq = blockIdx.x;
    if (bq < B_DIM / 4) {
        const int row = bq * 4 + wave;
        const float4* xr = (const float4*)(x + (size_t)row * IN_DIM);
        int* sr = (int*)(sx + (size_t)row * IN_DIM);
        float asum = 0.f;
#pragma unroll
        for (int it = 0; it < 4; ++it) {
            float4 v = xr[it * 64 + lane];
            asum += fabsf(v.x) + fabsf(v.y) + fabsf(v.z) + fabsf(v.w);
            sr[it * 64 + lane] =
                sgnb(v.x) | (sgnb(v.y) << 8) | (sgnb(v.z) << 16) | (sgnb(v.w) << 24);
        }
#pragma unroll
        for (int off = 32; off >= 1; off >>= 1) asum += __shfl_xor(asum, off, 64);
        if (lane == 0) xscale[row] = asum * (1.0f / IN_DIM);
    } else {
        const int row = (bq - B_DIM / 4) * 4 + wave;
        const float4* wr = (const float4*)(w + (size_t)row * IN_DIM);
        const float4* gr = (const float4*)(g + (size_t)row * IN_DIM);
        int* sr = (int*)(wb + (size_t)row * IN_DIM);
        float asum = 0.f;
#pragma unroll
        for (int it = 0; it < 4; ++it) {
            float4 wv = wr[it * 64 + lane];
            float4 gv = gr[it * 64 + lane];
            asum += fabsf(wv.x) + fabsf(wv.y) + fabsf(wv.z) + fabsf(wv.w);
            sr[it * 64 + lane] = gsgnb(wv.x, gv.x) | (gsgnb(wv.y, gv.y) << 8) |
                                 (gsgnb(wv.z, gv.z) << 16) | (gsgnb(wv.w, gv.w) << 24);
        }
#pragma unroll
        for (int off = 32; off >= 1; off >>= 1) asum += __shfl_xor(asum, off, 64);
        if (lane == 0) wscale[row] = asum * (1.0f / IN_DIM);
    }
}

// i8 GEMM, 8-phase-style schedule: 256x256 tile, BK=64, 8 waves (2Mx4N),
// 2 phases per K-tile, counted vmcnt(2) (never 0 in main loop), raw barriers,
// setprio around MFMA, source-side LDS bank swizzle. dbuf LDS 64 KB.
__global__ __launch_bounds__(512, 2) void gemm_i8_kernel(
    const signed char* __restrict__ A,   // [B_DIM][IN] sign(x)
    const signed char* __restrict__ Bw,  // [OUT][IN]   gated sign(w)
    const float* __restrict__ xscale,    // [B_DIM]
    const float* __restrict__ wscale,    // [OUT]
    const float* __restrict__ bias,      // [OUT]
    float* __restrict__ out) {           // [B_DIM][OUT]
    __shared__ signed char smA[2][16384];  // [buf][ks*8192 + row*32 + khs]
    __shared__ signed char smB[2][16384];

    const int t = threadIdx.x;
    const int wave = t >> 6, lane = t & 63;
    // XCD-aware bijective swizzle: 512 blocks = 8 XCDs x 64-chunk.
    const int swz = (blockIdx.x & 7) * 64 + (blockIdx.x >> 3);
    const int bm = swz >> 2;  // 128 tiles along M
    const int bn = swz & 3;   // 4 tiles along N
    const int wr = wave >> 2, wc = wave & 3;
    const int r32 = lane & 31;
    // read-side swizzled 16B-slot offset within a 32B row
    const int kh_eff = ((lane >> 5) << 4) ^ (((lane >> 2) & 1) << 4);

    int aoff[4], boff[2];
#pragma unroll
    for (int m = 0; m < 4; ++m) aoff[m] = (wr * 128 + m * 32 + r32) * 32 + kh_eff;
#pragma unroll
    for (int n = 0; n < 2; ++n) boff[n] = (wc * 64 + n * 32 + r32) * 32 + kh_eff;

    // staging coords: linear LDS dest (wave*1024 + lane*16), inverse-swizzled
    // global source so that swizzled read recovers the logical fragment.
    const int soff = wave * 1024 + lane * 16;
    const int s_row = soff >> 5;
    const int s_kh = (soff & 16) ^ (((s_row >> 2) & 1) << 4);
    const size_t arow0 = (size_t)bm * 256;
    const size_t brow0 = (size_t)bn * 256;
    const signed char* aSrc = A + (((size_t)(arow0 + s_row)) << 10) + s_kh;
    const signed char* bSrc = Bw + (((size_t)(brow0 + s_row)) << 10) + s_kh;

    v16i acc[4][2];
#pragma unroll
    for (int m = 0; m < 4; ++m)
#pragma unroll
        for (int n = 0; n < 2; ++n)
#pragma unroll
            for (int j = 0; j < 16; ++j) acc[m][n][j] = 0;

#define ISSUE_A(P, KS, K0)                                                      \
    __builtin_amdgcn_global_load_lds(                                           \
        (const __attribute__((address_space(1))) void*)(aSrc + (K0) + (KS)*32), \
        (__attribute__((address_space(3))) void*)(&smA[P][(KS)*8192] + wave * 1024), \
        16, 0, 0)
#define ISSUE_B(P, KS, K0)                                                      \
    __builtin_amdgcn_global_load_lds(                                           \
        (const __attribute__((address_space(1))) void*)(bSrc + (K0) + (KS)*32), \
        (__attribute__((address_space(3))) void*)(&smB[P][(KS)*8192] + wave * 1024), \
        16, 0, 0)

// One phase: ds_read quadrant of buf P (k-sub KS), optionally prefetch the
// same k-sub units of the NEXT tile into buf P^1, barrier, MFMA cluster,
// counted vmcnt, barrier. VMASM is the (literal) wait statement.
#define PHASE(P, KS, DOPREF, K0N, VMASM)                                        \
    {                                                                           \
        v4i af[4], bf[2];                                                       \
        _Pragma("unroll") for (int m = 0; m < 4; ++m)                           \
            af[m] = *(const v4i*)(&smA[P][(KS)*8192] + aoff[m]);                \
        _Pragma("unroll") for (int n = 0; n < 2; ++n)                           \
            bf[n] = *(const v4i*)(&smB[P][(KS)*8192] + boff[n]);                \
        if (DOPREF) {                                                           \
            ISSUE_A((P) ^ 1, KS, K0N);                                          \
            ISSUE_B((P) ^ 1, KS, K0N);                                          \
        }                                                                       \
        __builtin_amdgcn_s_barrier();                                           \
        __builtin_amdgcn_s_setprio(1);                                          \
        _Pragma("unroll") for (int m = 0; m < 4; ++m) {                         \
            acc[m][0] = __builtin_amdgcn_mfma_i32_32x32x32_i8(af[m], bf[0],     \
                                                              acc[m][0], 0, 0, 0); \
            acc[m][1] = __builtin_amdgcn_mfma_i32_32x32x32_i8(af[m], bf[1],     \
                                                              acc[m][1], 0, 0, 0); \
        }                                                                       \
        __builtin_amdgcn_s_setprio(0);                                          \
        VMASM;                                                                  \
        __builtin_amdgcn_s_barrier();                                           \
    }

    // prologue: stage tile 0 (units Ak0,Bk0,Ak1,Bk1) into buf0; wait oldest 2.
    ISSUE_A(0, 0, 0);
    ISSUE_B(0, 0, 0);
    ISSUE_A(0, 1, 0);
    ISSUE_B(0, 1, 0);
    asm volatile("s_waitcnt vmcnt(2)" ::: "memory");
    __builtin_amdgcn_s_barrier();

#pragma unroll 1
    for (int kt = 0; kt < 14; kt += 2) {
        // tile kt (buf0), prefetch kt+1 -> buf1
        PHASE(0, 0, 1, (kt + 1) * 64, asm volatile("s_waitcnt vmcnt(2)" ::: "memory"));
        PHASE(0, 1, 1, (kt + 1) * 64, asm volatile("s_waitcnt vmcnt(2)" ::: "memory"));
        // tile kt+1 (buf1), prefetch kt+2 -> buf0
        PHASE(1, 0, 1, (kt + 2) * 64, asm volatile("s_waitcnt vmcnt(2)" ::: "memory"));
        PHASE(1, 1, 1, (kt + 2) * 64, asm volatile("s_waitcnt vmcnt(2)" ::: "memory"));
    }
    // tile 14 (buf0), prefetch tile 15 -> buf1
    PHASE(0, 0, 1, 15 * 64, asm volatile("s_waitcnt vmcnt(2)" ::: "memory"));
    PHASE(0, 1, 1, 15 * 64, asm volatile("s_waitcnt vmcnt(2)" ::: "memory"));
    // tile 15 (buf1): no prefetch; drain remaining 2 units before its k-sub 1.
    PHASE(1, 0, 0, 0, asm volatile("s_waitcnt vmcnt(0)" ::: "memory"));
    PHASE(1, 1, 0, 0, (void)0);

#undef PHASE
#undef ISSUE_A
#undef ISSUE_B

    // epilogue: 32x32 C/D map col=lane&31, row=(reg&3)+8*(reg>>2)+4*(lane>>5)
    const int col = lane & 31;
    const int rb = 4 * (lane >> 5);
    float wsc[2], bv[2];
    int gcolv[2];
#pragma unroll
    for (int n = 0; n < 2; ++n) {
        gcolv[n] = bn * 256 + wc * 64 + n * 32 + col;
        wsc[n] = wscale[gcolv[n]];
        bv[n] = bias[gcolv[n]];
    }
#pragma unroll
    for (int m = 0; m < 4; ++m) {
#pragma unroll
        for (int j = 0; j < 16; ++j) {
            const int grow = bm * 256 + wr * 128 + m * 32 + (j & 3) + 8 * (j >> 2) + rb;
            const float is = xscale[grow];
#pragma unroll
            for (int n = 0; n < 2; ++n) {
                out[(size_t)grow * OUT_DIM + gcolv[n]] =
                    is * wsc[n] * ((float)acc[m][n][j] + bv[n]);
            }
        }
    }
}

extern "C" void kernel_launch(void* const* d_in, const int* in_sizes, int n_in,
                              void* d_out, int out_size, void* d_ws, size_t ws_size,
                              hipStream_t stream) {
    const float* x = (const float*)d_in[0];
    const float* w = (const float*)d_in[1];
    const float* g = (const float*)d_in[2];
    const float* bias = (const float*)d_in[3];
    float* out = (float*)d_out;

    // workspace layout (16B-aligned)
    signed char* sx = (signed char*)d_ws;                       // 33554432 B
    signed char* wb = sx + (size_t)B_DIM * IN_DIM;              //  1048576 B
    float* xscale = (float*)(wb + (size_t)OUT_DIM * IN_DIM);    //   131072 B
    float* wscale = xscale + B_DIM;                             //     4096 B

    prep_kernel<<<B_DIM / 4 + OUT_DIM / 4, 256, 0, stream>>>(x, w, g, sx, wb,
                                                             xscale, wscale);
    gemm_i8_kernel<<<(B_DIM / 256) * (OUT_DIM / 256), 512, 0, stream>>>(
        sx, wb, xscale, wscale, bias, out);
}

// Round 5
// 283.650 us; speedup vs baseline: 1.0164x; 1.0164x over previous
//
#include <hip/hip_runtime.h>

#define B_DIM 32768
#define IN_DIM 1024
#define OUT_DIM 1024

typedef int v4i __attribute__((ext_vector_type(4)));
typedef int v16i __attribute__((ext_vector_type(16)));

__device__ __forceinline__ int sgnb(float v) {
    return (v > 0.f) ? 1 : ((v < 0.f) ? 0xff : 0);
}
__device__ __forceinline__ int gsgnb(float w, float g) {
    return (g < 0.f) ? 0 : sgnb(w);
}

// Blocks [0, 8192): binarize x rows (4 rows/block, 1 wave/row) + in_scale.
// Blocks [8192, 8448): binarize weight*gate rows + weight_scale.
__global__ __launch_bounds__(256) void prep_kernel(
    const float* __restrict__ x, const float* __restrict__ w,
    const float* __restrict__ g,
    signed char* __restrict__ sx, signed char* __restrict__ wb,
    float* __restrict__ xscale, float* __restrict__ wscale) {
    const int wave = threadIdx.x >> 6;
    const int lane = threadIdx.x & 63;
    const int bq = blockIdx.x;
    if (bq < B_DIM / 4) {
        const int row = bq * 4 + wave;
        const float4* xr = (const float4*)(x + (size_t)row * IN_DIM);
        int* sr = (int*)(sx + (size_t)row * IN_DIM);
        float asum = 0.f;
#pragma unroll
        for (int it = 0; it < 4; ++it) {
            float4 v = xr[it * 64 + lane];
            asum += fabsf(v.x) + fabsf(v.y) + fabsf(v.z) + fabsf(v.w);
            sr[it * 64 + lane] =
                sgnb(v.x) | (sgnb(v.y) << 8) | (sgnb(v.z) << 16) | (sgnb(v.w) << 24);
        }
#pragma unroll
        for (int off = 32; off >= 1; off >>= 1) asum += __shfl_xor(asum, off, 64);
        if (lane == 0) xscale[row] = asum * (1.0f / IN_DIM);
    } else {
        const int row = (bq - B_DIM / 4) * 4 + wave;
        const float4* wr = (const float4*)(w + (size_t)row * IN_DIM);
        const float4* gr = (const float4*)(g + (size_t)row * IN_DIM);
        int* sr = (int*)(wb + (size_t)row * IN_DIM);
        float asum = 0.f;
#pragma unroll
        for (int it = 0; it < 4; ++it) {
            float4 wv = wr[it * 64 + lane];
            float4 gv = gr[it * 64 + lane];
            asum += fabsf(wv.x) + fabsf(wv.y) + fabsf(wv.z) + fabsf(wv.w);
            sr[it * 64 + lane] = gsgnb(wv.x, gv.x) | (gsgnb(wv.y, gv.y) << 8) |
                                 (gsgnb(wv.z, gv.z) << 16) | (gsgnb(wv.w, gv.w) << 24);
        }
#pragma unroll
        for (int off = 32; off >= 1; off >>= 1) asum += __shfl_xor(asum, off, 64);
        if (lane == 0) wscale[row] = asum * (1.0f / IN_DIM);
    }
}

// i8 GEMM, deep-pipelined: 256x256 tile, BK=64, 8 waves (2Mx4N), 4-deep LDS
// ring (tile j+3 prefetched while computing tile j), counted vmcnt(8) once
// per K-tile (never 0 in steady state), conflict-free swizzled ds_read,
// setprio around MFMA. LDS 128 KiB -> 1 block/CU.
__global__ __launch_bounds__(512, 2) void gemm_i8_kernel(
    const signed char* __restrict__ A,   // [B_DIM][IN] sign(x)
    const signed char* __restrict__ Bw,  // [OUT][IN]   gated sign(w)
    const float* __restrict__ xscale,    // [B_DIM]
    const float* __restrict__ wscale,    // [OUT]
    const float* __restrict__ bias,      // [OUT]
    float* __restrict__ out) {           // [B_DIM][OUT]
    // ring of 4 K-tiles; per tile: A = 256 rows x 64 B, B same. Byte layout
    // addr = row*64 + (c ^ (((row>>1)&3)<<4))  (read-side swizzle; staged via
    // inverse-swizzled global source, linear LDS dest -> rule #21 satisfied).
    __shared__ signed char smA[4][16384];
    __shared__ signed char smB[4][16384];

    const int t = threadIdx.x;
    const int wave = t >> 6, lane = t & 63;
    // XCD-aware bijective swizzle: 512 blocks = 8 XCDs x 64-chunk.
    const int swz = (blockIdx.x & 7) * 64 + (blockIdx.x >> 3);
    const int bm = swz >> 2;  // 128 tiles along M
    const int bn = swz & 3;   // 4 tiles along N
    const int wr = wave >> 2, wc = wave & 3;
    const int r32 = lane & 31;
    const int kh = (lane >> 5) << 4;
    const int fsw = ((r32 >> 1) & 3) << 4;   // row-derived slot swizzle
    const int c0 = kh ^ fsw;                 // swizzled 16B-slot for ks=0

    int aoff[4], boff[2];
#pragma unroll
    for (int m = 0; m < 4; ++m) aoff[m] = (wr * 128 + m * 32 + r32) * 64 + c0;
#pragma unroll
    for (int n = 0; n < 2; ++n) boff[n] = (wc * 64 + n * 32 + r32) * 64 + c0;

    // staging: issue i covers LDS bytes [i*8192 + t*16, +16). s_row = t>>2
    // (+128 for issue 1), s_c = ((t&3) ^ ((t>>3)&3)) << 4 (same both issues).
    const int sc = (((t & 3) ^ ((t >> 3) & 3)) << 4);
    const signed char* aS = A + ((size_t)(bm * 256 + (t >> 2)) << 10) + sc;
    const signed char* bS = Bw + ((size_t)(bn * 256 + (t >> 2)) << 10) + sc;
    const int ldsW = wave * 1024;  // wave-uniform dest base (lane*16 implicit)

    v16i acc[4][2];
#pragma unroll
    for (int m = 0; m < 4; ++m)
#pragma unroll
        for (int n = 0; n < 2; ++n)
#pragma unroll
            for (int j = 0; j < 16; ++j) acc[m][n][j] = 0;

#define GLDS(SRC, DST)                                                          \
    __builtin_amdgcn_global_load_lds(                                           \
        (const __attribute__((address_space(1))) void*)(SRC),                   \
        (__attribute__((address_space(3))) void*)(DST), 16, 0, 0)
#define ISSUE_A(NB, KT)                                                         \
    do {                                                                        \
        GLDS(aS + (KT)*64, &smA[NB][ldsW]);                                     \
        GLDS(aS + 131072 + (KT)*64, &smA[NB][8192 + ldsW]);                     \
    } while (0)
#define ISSUE_B(NB, KT)                                                         \
    do {                                                                        \
        GLDS(bS + (KT)*64, &smB[NB][ldsW]);                                     \
        GLDS(bS + 131072 + (KT)*64, &smB[NB][8192 + ldsW]);                     \
    } while (0)

// Phase: 6 ds_read_b128 -> issue prefetch -> barrier -> MFMA cluster -> WAIT
// -> barrier. KS selects the 32B k-half via XOR (bit 5).
#define PHASE(BUF, KS, ISSUES, WAITS)                                           \
    {                                                                           \
        v4i af[4], bf[2];                                                       \
        _Pragma("unroll") for (int m = 0; m < 4; ++m)                           \
            af[m] = *(const v4i*)(&smA[BUF][aoff[m] ^ ((KS) << 5)]);            \
        _Pragma("unroll") for (int n = 0; n < 2; ++n)                           \
            bf[n] = *(const v4i*)(&smB[BUF][boff[n] ^ ((KS) << 5)]);            \
        ISSUES;                                                                 \
        __builtin_amdgcn_s_barrier();                                           \
        __builtin_amdgcn_s_setprio(1);                                          \
        _Pragma("unroll") for (int m = 0; m < 4; ++m) {                         \
            acc[m][0] = __builtin_amdgcn_mfma_i32_32x32x32_i8(af[m], bf[0],     \
                                                              acc[m][0], 0, 0, 0); \
            acc[m][1] = __builtin_amdgcn_mfma_i32_32x32x32_i8(af[m], bf[1],     \
                                                              acc[m][1], 0, 0, 0); \
        }                                                                       \
        __builtin_amdgcn_s_setprio(0);                                          \
        WAITS;                                                                  \
        __builtin_amdgcn_s_barrier();                                           \
    }

    // prologue: stage tiles 0,1,2 (12 loads); wait all-but-8 -> tile 0 landed.
    ISSUE_A(0, 0);
    ISSUE_B(0, 0);
    ISSUE_A(1, 1);
    ISSUE_B(1, 1);
    ISSUE_A(2, 2);
    ISSUE_B(2, 2);
    asm volatile("s_waitcnt vmcnt(8)" ::: "memory");
    __builtin_amdgcn_s_barrier();

    // steady state: tiles 0..12, prefetch tile j+3, vmcnt(8) per tile ->
    // tile j+1 guaranteed landed, 2 tiles (8 loads) stay in flight.
#pragma unroll 1
    for (int j = 0; j < 13; ++j) {
        const int buf = j & 3;
        const int nbuf = (j + 3) & 3;
        const int kn = (j + 3) * 64;
        PHASE(buf, 0, ISSUE_A(nbuf, kn / 64 * 64 / 64), (void)0);
        PHASE(buf, 1, ISSUE_B(nbuf, kn / 64 * 64 / 64), asm volatile("s_waitcnt vmcnt(8)" ::: "memory"));
    }
    // tail: tiles 13,14,15 — drain 8 -> 4 -> 0.
    PHASE(1, 0, (void)0, (void)0);
    PHASE(1, 1, (void)0, asm volatile("s_waitcnt vmcnt(4)" ::: "memory"));
    PHASE(2, 0, (void)0, (void)0);
    PHASE(2, 1, (void)0, asm volatile("s_waitcnt vmcnt(0)" ::: "memory"));
    PHASE(3, 0, (void)0, (void)0);
    PHASE(3, 1, (void)0, (void)0);

#undef PHASE
#undef ISSUE_A
#undef ISSUE_B
#undef GLDS

    // epilogue: 32x32 C/D map col=lane&31, row=(reg&3)+8*(reg>>2)+4*(lane>>5)
    const int col = lane & 31;
    const int rb = 4 * (lane >> 5);
    float wsc[2], bv[2];
    int gcolv[2];
#pragma unroll
    for (int n = 0; n < 2; ++n) {
        gcolv[n] = bn * 256 + wc * 64 + n * 32 + col;
        wsc[n] = wscale[gcolv[n]];
        bv[n] = bias[gcolv[n]];
    }
#pragma unroll
    for (int m = 0; m < 4; ++m) {
#pragma unroll
        for (int j = 0; j < 16; ++j) {
            const int grow = bm * 256 + wr * 128 + m * 32 + (j & 3) + 8 * (j >> 2) + rb;
            const float is = xscale[grow];
#pragma unroll
            for (int n = 0; n < 2; ++n) {
                out[(size_t)grow * OUT_DIM + gcolv[n]] =
                    is * wsc[n] * ((float)acc[m][n][j] + bv[n]);
            }
        }
    }
}

extern "C" void kernel_launch(void* const* d_in, const int* in_sizes, int n_in,
                              void* d_out, int out_size, void* d_ws, size_t ws_size,
                              hipStream_t stream) {
    const float* x = (const float*)d_in[0];
    const float* w = (const float*)d_in[1];
    const float* g = (const float*)d_in[2];
    const float* bias = (const float*)d_in[3];
    float* out = (float*)d_out;

    // workspace layout (16B-aligned)
    signed char* sx = (signed char*)d_ws;                       // 33554432 B
    signed char* wb = sx + (size_t)B_DIM * IN_DIM;              //  1048576 B
    float* xscale = (float*)(wb + (size_t)OUT_DIM * IN_DIM);    //   131072 B
    float* wscale = xscale + B_DIM;                             //     4096 B

    prep_kernel<<<B_DIM / 4 + OUT_DIM / 4, 256, 0, stream>>>(x, w, g, sx, wb,
                                                             xscale, wscale);
    gemm_i8_kernel<<<(B_DIM / 256) * (OUT_DIM / 256), 512, 0, stream>>>(
        sx, wb, xscale, wscale, bias, out);
}